// Round 15
// baseline (518.057 us; speedup 1.0000x reference)
//
#include <hip/hip_runtime.h>

typedef unsigned int u32;
typedef unsigned long long u64;
typedef double f64x4 __attribute__((ext_vector_type(4)));

#define NHEAD 8
#define NTOK 65536
#define DIM 128
#define MBLK 1024
#define KKEEP 52

// ---------------- coarsen: pick max-L2 token per 64-token block (q and k fused) --------
__global__ __launch_bounds__(256) void coarsen_kernel(const float* __restrict__ q,
                                                      const float* __restrict__ k,
                                                      float* __restrict__ qc,
                                                      float* __restrict__ kc) {
    int bb = blockIdx.x;             // 0..16383 ; first half q, second half k
    const float* x = (bb < 8192) ? q : k;
    float* xc = (bb < 8192) ? qc : kc;
    int b = bb & 8191;
    int h = b >> 10, mb = b & 1023;
    const float4* b4 = (const float4*)(x + ((size_t)h * NTOK + (size_t)mb * 64) * DIM);
    int tid = threadIdx.x;

    __shared__ double norms[64];
    __shared__ int best;

    #pragma unroll
    for (int u = 0; u < 8; ++u) {
        int f = tid + u * 256;               // f>>5 = token, f&31 = lane's f4 within token
        float4 v = b4[f];
        double s = (double)v.x * v.x + (double)v.y * v.y + (double)v.z * v.z + (double)v.w * v.w;
        #pragma unroll
        for (int off = 1; off < 32; off <<= 1) s += __shfl_xor(s, off);
        if ((tid & 31) == 0) norms[f >> 5] = s;
    }
    __syncthreads();

    if (tid < 64) {   // wave 0: argmax with first-index tie-break
        double v = norms[tid]; int idx = tid;
        #pragma unroll
        for (int off = 32; off; off >>= 1) {
            double ov = __shfl_down(v, off);
            int oi = __shfl_down(idx, off);
            if (ov > v || (ov == v && oi < idx)) { v = ov; idx = oi; }
        }
        if (tid == 0) best = idx;
    }
    __syncthreads();

    if (tid < 32) {
        float4* dst = (float4*)(xc + ((size_t)h * MBLK + mb) * DIM);
        dst[tid] = b4[best * 32 + tid];
    }
}

// ------- affinity via f64 MFMA: A[h] = relu(qc kc^T * scale) + per-tile degree partials
// 64x64 tile, 256 threads (4 waves, wave = 16 rows x 64 cols, acc = 4 f64x4 = 16 AGPR).
// K=128 staged in 4 chunks of 32 (same staging as the proven VALU version); MFMA frags
// addressed exactly like tri (A: row=lr,k=lk from qs[d][i]; B: col=lr,k=lk from ks[d][j]).
// Epilogue is layout-agnostic: probed (prow,pcol) scatter into an LDS tile, then
// coalesced C-write + fixed-order row/col sums (deterministic fp64).
__global__ __launch_bounds__(256) void affinity_kernel(const float* __restrict__ qc,
                                                       const float* __restrict__ kc,
                                                       double* __restrict__ A,
                                                       double* __restrict__ pout,
                                                       double* __restrict__ pin) {
    __shared__ double qs[32][70];    // [d][i], padded
    __shared__ double ks[32][70];    // [d][j]
    __shared__ double tile[64][65];  // scatter target (33 KB)
    int b = blockIdx.x;              // 8 * 16 * 16 = 2048
    int h = b >> 8, ti = (b >> 4) & 15, tj = b & 15;
    int i0 = ti * 64, j0 = tj * 64;
    int tid = threadIdx.x;
    int wv = tid >> 6, lane = tid & 63;
    int lr = lane & 15, lk = lane >> 4;

    // ---- layout probe: D[i][j] = i*16 + j (exact integers) ----
    f64x4 probe = {0.0, 0.0, 0.0, 0.0};
    #pragma unroll
    for (int t = 0; t < 4; ++t) {
        double pa = (lr == 4 * t + lk) ? 1.0 : 0.0;
        double pb = (double)((4 * t + lk) * 16 + lr);
        probe = __builtin_amdgcn_mfma_f64_16x16x4f64(pa, pb, probe, 0, 0, 0);
    }
    int prow[4], pcol[4];
    #pragma unroll
    for (int g = 0; g < 4; ++g) {
        int v = (int)probe[g];
        prow[g] = v >> 4;
        pcol[g] = v & 15;
    }

    f64x4 acc[4];
    #pragma unroll
    for (int c = 0; c < 4; ++c) {
        f64x4 z = {0.0, 0.0, 0.0, 0.0};
        acc[c] = z;
    }

    const float4* qg = (const float4*)(qc + ((size_t)h * MBLK + i0) * DIM);
    const float4* kg = (const float4*)(kc + ((size_t)h * MBLK + j0) * DIM);

    for (int dk = 0; dk < 4; ++dk) {        // K=128 in chunks of 32
        __syncthreads();
        #pragma unroll
        for (int u = 0; u < 2; ++u) {
            int f = tid + u * 256;          // 0..511 ; row = f>>3, dp = f&7
            int row = f >> 3, dp = f & 7;
            float4 qv = qg[row * 32 + dk * 8 + dp];
            float4 kv = kg[row * 32 + dk * 8 + dp];
            int d0 = dp * 4;
            qs[d0 + 0][row] = qv.x; qs[d0 + 1][row] = qv.y;
            qs[d0 + 2][row] = qv.z; qs[d0 + 3][row] = qv.w;
            ks[d0 + 0][row] = kv.x; ks[d0 + 1][row] = kv.y;
            ks[d0 + 2][row] = kv.z; ks[d0 + 3][row] = kv.w;
        }
        __syncthreads();
        #pragma unroll
        for (int kc8 = 0; kc8 < 8; ++kc8) {
            int d = kc8 * 4 + lk;
            double af = qs[d][wv * 16 + lr];
            double bf[4];
            #pragma unroll
            for (int c = 0; c < 4; ++c) bf[c] = ks[d][c * 16 + lr];
            #pragma unroll
            for (int c = 0; c < 4; ++c)
                acc[c] = __builtin_amdgcn_mfma_f64_16x16x4f64(af, bf[c], acc[c], 0, 0, 0);
        }
    }

    __syncthreads();   // qs/ks staging done; safe to reuse LDS phase for tile scatter
    const double scale = 1.0 / sqrt(128.0);   // IEEE-exact, matches python
    #pragma unroll
    for (int g = 0; g < 4; ++g)
        #pragma unroll
        for (int c = 0; c < 4; ++c) {
            double v = acc[c][g] * scale;
            tile[wv * 16 + prow[g]][c * 16 + pcol[g]] = (v < 0.0) ? 0.0 : v;
        }
    __syncthreads();

    // coalesced C write: 2048 double2, 8 per thread
    #pragma unroll
    for (int u = 0; u < 8; ++u) {
        int f = tid + u * 256;
        int row = f >> 5, cp = f & 31;
        double2 v; v.x = tile[row][cp * 2]; v.y = tile[row][cp * 2 + 1];
        *(double2*)&A[((size_t)h << 20) + ((size_t)(i0 + row) << 10) + j0 + cp * 2] = v;
    }

    // fixed-order degree partials (deterministic)
    int hidx = h * 16;
    if (tid < 64) {
        double s = 0.0;
        #pragma unroll 8
        for (int c = 0; c < 64; ++c) s += tile[tid][c];
        pout[(((size_t)(hidx + ti) * 16 + tj) << 6) + tid] = s;
    } else if (tid < 128) {
        int c = tid - 64;
        double s = 0.0;
        #pragma unroll 8
        for (int r = 0; r < 64; ++r) s += tile[r][c];
        pin[(((size_t)(hidx + tj) * 16 + ti) << 6) + c] = s;
    }
}

// ---------------- degree reduce: fixed-order 16-term sums (deterministic) ----------------
__global__ __launch_bounds__(256) void deg_reduce_kernel(const double* __restrict__ pout,
                                                         const double* __restrict__ pin,
                                                         double* __restrict__ dgo,
                                                         double* __restrict__ dgi) {
    int t = blockIdx.x * 256 + threadIdx.x;   // 0..16383
    const double* src = (t < 8192) ? pout : pin;
    double* dst = (t < 8192) ? dgo : dgi;
    int r = t & 8191;
    int hi = r >> 6, rr = r & 63;
    double s = 0.0;
    #pragma unroll
    for (int tj = 0; tj < 16; ++tj) s += src[(((size_t)hi * 16 + tj) << 6) + rr];
    dst[r] = s;
}

// ---- async global->LDS helper (16B per lane; LDS dest = wave-uniform base + lane*16) ----
__device__ inline void gll16(const double* g, double* lds_base) {
    __builtin_amdgcn_global_load_lds((const __attribute__((address_space(1))) void*)g,
                                     (__attribute__((address_space(3))) void*)lds_base,
                                     16, 0, 0);
}

// ---------------- triangles + neg_frc: fp64 MFMA, dbuf via global_load_lds ----------------
// (unchanged from R12: 302 us, MfmaUtil 77.5%)
__global__ __launch_bounds__(512, 4) void tri_kernel(const double* __restrict__ A,
                                                     const double* __restrict__ dout,
                                                     const double* __restrict__ din,
                                                     double* __restrict__ neg) {
    __shared__ double lds[2][2][2048];   // [buf][0=A,1=B][2048 doubles] = 64 KB
    int h = blockIdx.z, ti = blockIdx.y, tj = blockIdx.x;
    int i0 = ti * 128, j0 = tj * 128;
    int tid = threadIdx.x;
    int wv = tid >> 6, lane = tid & 63;
    int lr = lane & 15, lk = lane >> 4;

    // ---- layout probe: D[i][j] = i*16 + j ----
    f64x4 probe = {0.0, 0.0, 0.0, 0.0};
    #pragma unroll
    for (int t = 0; t < 4; ++t) {
        double pa = (lr == 4 * t + lk) ? 1.0 : 0.0;
        double pb = (double)((4 * t + lk) * 16 + lr);
        probe = __builtin_amdgcn_mfma_f64_16x16x4f64(pa, pb, probe, 0, 0, 0);
    }
    int prow[4], pcol[4];
    #pragma unroll
    for (int g = 0; g < 4; ++g) {
        int v = (int)probe[g];
        prow[g] = v >> 4;
        pcol[g] = v & 15;
    }

    f64x4 acc[8];
    #pragma unroll
    for (int c = 0; c < 8; ++c) {
        f64x4 z = {0.0, 0.0, 0.0, 0.0};
        acc[c] = z;
    }

    const double* Ah = A + ((size_t)h << 20);

    int aRow[2], aPos[2], bRow[2], bPos[2];
    #pragma unroll
    for (int u = 0; u < 2; ++u) {
        int f = tid + u * 512;
        aRow[u] = f >> 3;  aPos[u] = f & 7;    // A tile: 128 rows x 8 chunks
        bRow[u] = f >> 6;  bPos[u] = f & 63;   // B tile: 16 rows x 64 chunks
    }

    #define ISSUE_TILE(BUF, KT)                                                        \
    {                                                                                  \
        int kt_ = (KT);                                                                \
        _Pragma("unroll")                                                              \
        for (int u = 0; u < 2; ++u) {                                                  \
            const double* gA = Ah + (size_t)(i0 + aRow[u]) * 1024 + kt_                \
                               + 2 * (aPos[u] ^ (aRow[u] & 7));                        \
            gll16(gA, &lds[BUF][0][(size_t)(wv * 64 + u * 512) * 2]);                  \
            const double* gB = Ah + (size_t)(kt_ + bRow[u]) * 1024 + j0 + 2 * bPos[u]; \
            gll16(gB, &lds[BUF][1][(size_t)(wv * 64 + u * 512) * 2]);                  \
        }                                                                              \
    }

    ISSUE_TILE(0, 0);
    __syncthreads();

    int cur = 0;
    for (int kt = 0; kt < 1024; kt += 16) {
        if (kt + 16 < 1024) ISSUE_TILE(cur ^ 1, kt + 16);

        const double* asub_d = &lds[cur][0][0];
        const double* bsub_d = &lds[cur][1][0];
        __builtin_amdgcn_s_setprio(1);
        #pragma unroll
        for (int ks = 0; ks < 4; ++ks) {
            int k = ks * 4 + lk;
            int i = wv * 16 + lr;
            double af = asub_d[i * 16 + ((k >> 1) ^ (i & 7)) * 2 + (k & 1)];
            double bf[8];
            #pragma unroll
            for (int c = 0; c < 8; ++c) bf[c] = bsub_d[k * 128 + c * 16 + lr];
            #pragma unroll
            for (int c = 0; c < 8; ++c)
                acc[c] = __builtin_amdgcn_mfma_f64_16x16x4f64(af, bf[c], acc[c], 0, 0, 0);
        }
        __builtin_amdgcn_s_setprio(0);

        __syncthreads();
        cur ^= 1;
    }
    #undef ISSUE_TILE

    #pragma unroll
    for (int g = 0; g < 4; ++g) {
        int i = i0 + wv * 16 + prow[g];
        double doi = dout[h * MBLK + i] - 4.0;
        #pragma unroll
        for (int c = 0; c < 8; ++c) {
            int j = j0 + c * 16 + pcol[g];
            neg[((size_t)h << 20) + ((size_t)i << 10) + j] =
                doi + din[h * MBLK + j] - 0.5 * acc[c][g];
        }
    }
}

// ---------------- exact k-th largest + mask, single wave per row (no barriers) ----------
__device__ inline u64 sortable64(double f) {
    u64 b = (u64)__double_as_longlong(f);
    return (b & 0x8000000000000000ull) ? ~b : (b | 0x8000000000000000ull);
}

__global__ __launch_bounds__(64) void topk_mask_kernel(const double* __restrict__ neg,
                                                       int* __restrict__ out) {
    int r = blockIdx.x;            // 8192 rows
    int l = threadIdx.x;           // 64 lanes
    const double* row = neg + ((size_t)r << 10);
    u64 v[16];
    #pragma unroll
    for (int m = 0; m < 16; ++m) v[m] = sortable64(row[l + m * 64]);

    u64 lo = 0, hi = ~0ull;
    while (lo < hi) {
        u64 span = hi - lo;
        u64 mid = lo + (span >> 1) + (span & 1);   // upper mid
        int c = 0;
        #pragma unroll
        for (int m = 0; m < 16; ++m) c += (int)(v[m] >= mid);
        #pragma unroll
        for (int off = 1; off < 64; off <<= 1) c += __shfl_xor(c, off);
        if (c >= KKEEP) lo = mid; else hi = mid - 1;   // uniform across lanes
    }

    int i = r & 1023;              // diagonal index within this head's MxM
    int* orow = out + ((size_t)r << 10);
    #pragma unroll
    for (int m = 0; m < 16; ++m)
        orow[l + m * 64] = (v[m] >= lo || (l + m * 64) == i) ? 1 : 0;
}

extern "C" void kernel_launch(void* const* d_in, const int* in_sizes, int n_in,
                              void* d_out, int out_size, void* d_ws, size_t ws_size,
                              hipStream_t stream) {
    const float* q = (const float*)d_in[0];
    const float* k = (const float*)d_in[1];
    int* out = (int*)d_out;
    char* ws = (char*)d_ws;

    float*  qc   = (float*)ws;                            //  4 MB
    float*  kc   = (float*)(ws + (4ull << 20));           //  4 MB
    double* A    = (double*)(ws + (8ull << 20));          // 64 MB
    double* neg  = (double*)(ws + (72ull << 20));         // 64 MB
    double* dgo  = (double*)(ws + (136ull << 20));        // 64 KB
    double* dgi  = dgo + 8192;                            // 64 KB
    double* pout = dgi + 8192;                            //  1 MB (8*16*16*64 doubles)
    double* pin  = pout + 131072;                         //  1 MB

    coarsen_kernel<<<16384, 256, 0, stream>>>(q, k, qc, kc);
    affinity_kernel<<<2048, 256, 0, stream>>>(qc, kc, A, pout, pin);
    deg_reduce_kernel<<<64, 256, 0, stream>>>(pout, pin, dgo, dgi);
    tri_kernel<<<dim3(8, 8, 8), 512, 0, stream>>>(A, dgo, dgi, neg);
    topk_mask_kernel<<<8192, 64, 0, stream>>>(neg, out);
}

// Round 16
// 514.362 us; speedup vs baseline: 1.0072x; 1.0072x over previous
//
#include <hip/hip_runtime.h>

typedef unsigned int u32;
typedef unsigned long long u64;
typedef double f64x4 __attribute__((ext_vector_type(4)));

#define NHEAD 8
#define NTOK 65536
#define DIM 128
#define MBLK 1024
#define KKEEP 52

// ---------------- coarsen: pick max-L2 token per 64-token block (q and k fused) --------
// LDS partial-sum reduction instead of per-fragment shfl trees: 8 ds_write + 12 ds_read
// per thread replaces 80 permute-pipe ops (fp64 shfl = 2 ops each). Fixed summation
// order (deterministic); fp64 norms, ~1e-13 error vs O(1) inter-token gaps.
__global__ __launch_bounds__(256) void coarsen_kernel(const float* __restrict__ q,
                                                      const float* __restrict__ k,
                                                      float* __restrict__ qc,
                                                      float* __restrict__ kc) {
    int bb = blockIdx.x;             // 0..16383 ; first half q, second half k
    const float* x = (bb < 8192) ? q : k;
    float* xc = (bb < 8192) ? qc : kc;
    int b = bb & 8191;
    int h = b >> 10, mb = b & 1023;
    const float4* b4 = (const float4*)(x + ((size_t)h * NTOK + (size_t)mb * 64) * DIM);
    int tid = threadIdx.x;

    __shared__ double part[64][33];   // [token][32 fragment partials], odd-pad
    __shared__ double red2[64][5];    // [token][4 quarter sums]
    __shared__ double norms[64];
    __shared__ int best;

    // phase 1: per-fragment fp64 partial -> LDS (conflict-free: 2 tokens/wave, l32 dense)
    #pragma unroll
    for (int u = 0; u < 8; ++u) {
        int f = tid + u * 256;               // tok = f>>5, l32 = f&31
        float4 v = b4[f];
        double s = (double)v.x * v.x + (double)v.y * v.y + (double)v.z * v.z + (double)v.w * v.w;
        part[f >> 5][f & 31] = s;
    }
    __syncthreads();

    // phase 2a: each thread sums 8 partials of (tok = tid>>2, quarter = tid&3)
    {
        int tok = tid >> 2, qq = tid & 3;
        double s = 0.0;
        #pragma unroll
        for (int m = 0; m < 8; ++m) s += part[tok][qq * 8 + m];
        red2[tok][qq] = s;
    }
    __syncthreads();

    // phase 2b + argmax (wave 0), first-index tie-break
    if (tid < 64) {
        double v = red2[tid][0] + red2[tid][1] + red2[tid][2] + red2[tid][3];
        norms[tid] = v;
        int idx = tid;
        #pragma unroll
        for (int off = 32; off; off >>= 1) {
            double ov = __shfl_down(v, off);
            int oi = __shfl_down(idx, off);
            if (ov > v || (ov == v && oi < idx)) { v = ov; idx = oi; }
        }
        if (tid == 0) best = idx;
    }
    __syncthreads();

    if (tid < 32) {
        float4* dst = (float4*)(xc + ((size_t)h * MBLK + mb) * DIM);
        dst[tid] = b4[best * 32 + tid];
    }
}

// ------- affinity via f64 MFMA: A[h] = relu(qc kc^T * scale) + per-tile degree partials
// (unchanged from R15 measured baseline)
__global__ __launch_bounds__(256) void affinity_kernel(const float* __restrict__ qc,
                                                       const float* __restrict__ kc,
                                                       double* __restrict__ A,
                                                       double* __restrict__ pout,
                                                       double* __restrict__ pin) {
    __shared__ double qs[32][70];    // [d][i], padded
    __shared__ double ks[32][70];    // [d][j]
    __shared__ double tile[64][65];  // scatter target (33 KB)
    int b = blockIdx.x;              // 8 * 16 * 16 = 2048
    int h = b >> 8, ti = (b >> 4) & 15, tj = b & 15;
    int i0 = ti * 64, j0 = tj * 64;
    int tid = threadIdx.x;
    int wv = tid >> 6, lane = tid & 63;
    int lr = lane & 15, lk = lane >> 4;

    // ---- layout probe: D[i][j] = i*16 + j (exact integers) ----
    f64x4 probe = {0.0, 0.0, 0.0, 0.0};
    #pragma unroll
    for (int t = 0; t < 4; ++t) {
        double pa = (lr == 4 * t + lk) ? 1.0 : 0.0;
        double pb = (double)((4 * t + lk) * 16 + lr);
        probe = __builtin_amdgcn_mfma_f64_16x16x4f64(pa, pb, probe, 0, 0, 0);
    }
    int prow[4], pcol[4];
    #pragma unroll
    for (int g = 0; g < 4; ++g) {
        int v = (int)probe[g];
        prow[g] = v >> 4;
        pcol[g] = v & 15;
    }

    f64x4 acc[4];
    #pragma unroll
    for (int c = 0; c < 4; ++c) {
        f64x4 z = {0.0, 0.0, 0.0, 0.0};
        acc[c] = z;
    }

    const float4* qg = (const float4*)(qc + ((size_t)h * MBLK + i0) * DIM);
    const float4* kg = (const float4*)(kc + ((size_t)h * MBLK + j0) * DIM);

    for (int dk = 0; dk < 4; ++dk) {        // K=128 in chunks of 32
        __syncthreads();
        #pragma unroll
        for (int u = 0; u < 2; ++u) {
            int f = tid + u * 256;          // 0..511 ; row = f>>3, dp = f&7
            int row = f >> 3, dp = f & 7;
            float4 qv = qg[row * 32 + dk * 8 + dp];
            float4 kv = kg[row * 32 + dk * 8 + dp];
            int d0 = dp * 4;
            qs[d0 + 0][row] = qv.x; qs[d0 + 1][row] = qv.y;
            qs[d0 + 2][row] = qv.z; qs[d0 + 3][row] = qv.w;
            ks[d0 + 0][row] = kv.x; ks[d0 + 1][row] = kv.y;
            ks[d0 + 2][row] = kv.z; ks[d0 + 3][row] = kv.w;
        }
        __syncthreads();
        #pragma unroll
        for (int kc8 = 0; kc8 < 8; ++kc8) {
            int d = kc8 * 4 + lk;
            double af = qs[d][wv * 16 + lr];
            double bf[4];
            #pragma unroll
            for (int c = 0; c < 4; ++c) bf[c] = ks[d][c * 16 + lr];
            #pragma unroll
            for (int c = 0; c < 4; ++c)
                acc[c] = __builtin_amdgcn_mfma_f64_16x16x4f64(af, bf[c], acc[c], 0, 0, 0);
        }
    }

    __syncthreads();   // qs/ks staging done; safe to reuse LDS phase for tile scatter
    const double scale = 1.0 / sqrt(128.0);   // IEEE-exact, matches python
    #pragma unroll
    for (int g = 0; g < 4; ++g)
        #pragma unroll
        for (int c = 0; c < 4; ++c) {
            double v = acc[c][g] * scale;
            tile[wv * 16 + prow[g]][c * 16 + pcol[g]] = (v < 0.0) ? 0.0 : v;
        }
    __syncthreads();

    // coalesced C write: 2048 double2, 8 per thread
    #pragma unroll
    for (int u = 0; u < 8; ++u) {
        int f = tid + u * 256;
        int row = f >> 5, cp = f & 31;
        double2 v; v.x = tile[row][cp * 2]; v.y = tile[row][cp * 2 + 1];
        *(double2*)&A[((size_t)h << 20) + ((size_t)(i0 + row) << 10) + j0 + cp * 2] = v;
    }

    // fixed-order degree partials (deterministic)
    int hidx = h * 16;
    if (tid < 64) {
        double s = 0.0;
        #pragma unroll 8
        for (int c = 0; c < 64; ++c) s += tile[tid][c];
        pout[(((size_t)(hidx + ti) * 16 + tj) << 6) + tid] = s;
    } else if (tid < 128) {
        int c = tid - 64;
        double s = 0.0;
        #pragma unroll 8
        for (int r = 0; r < 64; ++r) s += tile[r][c];
        pin[(((size_t)(hidx + tj) * 16 + ti) << 6) + c] = s;
    }
}

// ---------------- degree reduce: fixed-order 16-term sums (deterministic) ----------------
__global__ __launch_bounds__(256) void deg_reduce_kernel(const double* __restrict__ pout,
                                                         const double* __restrict__ pin,
                                                         double* __restrict__ dgo,
                                                         double* __restrict__ dgi) {
    int t = blockIdx.x * 256 + threadIdx.x;   // 0..16383
    const double* src = (t < 8192) ? pout : pin;
    double* dst = (t < 8192) ? dgo : dgi;
    int r = t & 8191;
    int hi = r >> 6, rr = r & 63;
    double s = 0.0;
    #pragma unroll
    for (int tj = 0; tj < 16; ++tj) s += src[(((size_t)hi * 16 + tj) << 6) + rr];
    dst[r] = s;
}

// ---- async global->LDS helper (16B per lane; LDS dest = wave-uniform base + lane*16) ----
__device__ inline void gll16(const double* g, double* lds_base) {
    __builtin_amdgcn_global_load_lds((const __attribute__((address_space(1))) void*)g,
                                     (__attribute__((address_space(3))) void*)lds_base,
                                     16, 0, 0);
}

// ---------------- triangles + neg_frc: fp64 MFMA, dbuf via global_load_lds ----------------
// (unchanged from R12: 302 us, MfmaUtil 77.5%)
__global__ __launch_bounds__(512, 4) void tri_kernel(const double* __restrict__ A,
                                                     const double* __restrict__ dout,
                                                     const double* __restrict__ din,
                                                     double* __restrict__ neg) {
    __shared__ double lds[2][2][2048];   // [buf][0=A,1=B][2048 doubles] = 64 KB
    int h = blockIdx.z, ti = blockIdx.y, tj = blockIdx.x;
    int i0 = ti * 128, j0 = tj * 128;
    int tid = threadIdx.x;
    int wv = tid >> 6, lane = tid & 63;
    int lr = lane & 15, lk = lane >> 4;

    // ---- layout probe: D[i][j] = i*16 + j ----
    f64x4 probe = {0.0, 0.0, 0.0, 0.0};
    #pragma unroll
    for (int t = 0; t < 4; ++t) {
        double pa = (lr == 4 * t + lk) ? 1.0 : 0.0;
        double pb = (double)((4 * t + lk) * 16 + lr);
        probe = __builtin_amdgcn_mfma_f64_16x16x4f64(pa, pb, probe, 0, 0, 0);
    }
    int prow[4], pcol[4];
    #pragma unroll
    for (int g = 0; g < 4; ++g) {
        int v = (int)probe[g];
        prow[g] = v >> 4;
        pcol[g] = v & 15;
    }

    f64x4 acc[8];
    #pragma unroll
    for (int c = 0; c < 8; ++c) {
        f64x4 z = {0.0, 0.0, 0.0, 0.0};
        acc[c] = z;
    }

    const double* Ah = A + ((size_t)h << 20);

    int aRow[2], aPos[2], bRow[2], bPos[2];
    #pragma unroll
    for (int u = 0; u < 2; ++u) {
        int f = tid + u * 512;
        aRow[u] = f >> 3;  aPos[u] = f & 7;    // A tile: 128 rows x 8 chunks
        bRow[u] = f >> 6;  bPos[u] = f & 63;   // B tile: 16 rows x 64 chunks
    }

    #define ISSUE_TILE(BUF, KT)                                                        \
    {                                                                                  \
        int kt_ = (KT);                                                                \
        _Pragma("unroll")                                                              \
        for (int u = 0; u < 2; ++u) {                                                  \
            const double* gA = Ah + (size_t)(i0 + aRow[u]) * 1024 + kt_                \
                               + 2 * (aPos[u] ^ (aRow[u] & 7));                        \
            gll16(gA, &lds[BUF][0][(size_t)(wv * 64 + u * 512) * 2]);                  \
            const double* gB = Ah + (size_t)(kt_ + bRow[u]) * 1024 + j0 + 2 * bPos[u]; \
            gll16(gB, &lds[BUF][1][(size_t)(wv * 64 + u * 512) * 2]);                  \
        }                                                                              \
    }

    ISSUE_TILE(0, 0);
    __syncthreads();

    int cur = 0;
    for (int kt = 0; kt < 1024; kt += 16) {
        if (kt + 16 < 1024) ISSUE_TILE(cur ^ 1, kt + 16);

        const double* asub_d = &lds[cur][0][0];
        const double* bsub_d = &lds[cur][1][0];
        __builtin_amdgcn_s_setprio(1);
        #pragma unroll
        for (int ks = 0; ks < 4; ++ks) {
            int k = ks * 4 + lk;
            int i = wv * 16 + lr;
            double af = asub_d[i * 16 + ((k >> 1) ^ (i & 7)) * 2 + (k & 1)];
            double bf[8];
            #pragma unroll
            for (int c = 0; c < 8; ++c) bf[c] = bsub_d[k * 128 + c * 16 + lr];
            #pragma unroll
            for (int c = 0; c < 8; ++c)
                acc[c] = __builtin_amdgcn_mfma_f64_16x16x4f64(af, bf[c], acc[c], 0, 0, 0);
        }
        __builtin_amdgcn_s_setprio(0);

        __syncthreads();
        cur ^= 1;
    }
    #undef ISSUE_TILE

    #pragma unroll
    for (int g = 0; g < 4; ++g) {
        int i = i0 + wv * 16 + prow[g];
        double doi = dout[h * MBLK + i] - 4.0;
        #pragma unroll
        for (int c = 0; c < 8; ++c) {
            int j = j0 + c * 16 + pcol[g];
            neg[((size_t)h << 20) + ((size_t)i << 10) + j] =
                doi + din[h * MBLK + j] - 0.5 * acc[c][g];
        }
    }
}

// ---------------- exact k-th largest + mask, single wave per row (no barriers) ----------
__device__ inline u64 sortable64(double f) {
    u64 b = (u64)__double_as_longlong(f);
    return (b & 0x8000000000000000ull) ? ~b : (b | 0x8000000000000000ull);
}

__global__ __launch_bounds__(64) void topk_mask_kernel(const double* __restrict__ neg,
                                                       int* __restrict__ out) {
    int r = blockIdx.x;            // 8192 rows
    int l = threadIdx.x;           // 64 lanes
    const double* row = neg + ((size_t)r << 10);
    u64 v[16];
    #pragma unroll
    for (int m = 0; m < 16; ++m) v[m] = sortable64(row[l + m * 64]);

    u64 lo = 0, hi = ~0ull;
    while (lo < hi) {
        u64 span = hi - lo;
        u64 mid = lo + (span >> 1) + (span & 1);   // upper mid
        int c = 0;
        #pragma unroll
        for (int m = 0; m < 16; ++m) c += (int)(v[m] >= mid);
        #pragma unroll
        for (int off = 1; off < 64; off <<= 1) c += __shfl_xor(c, off);
        if (c >= KKEEP) lo = mid; else hi = mid - 1;   // uniform across lanes
    }

    int i = r & 1023;              // diagonal index within this head's MxM
    int* orow = out + ((size_t)r << 10);
    #pragma unroll
    for (int m = 0; m < 16; ++m)
        orow[l + m * 64] = (v[m] >= lo || (l + m * 64) == i) ? 1 : 0;
}

extern "C" void kernel_launch(void* const* d_in, const int* in_sizes, int n_in,
                              void* d_out, int out_size, void* d_ws, size_t ws_size,
                              hipStream_t stream) {
    const float* q = (const float*)d_in[0];
    const float* k = (const float*)d_in[1];
    int* out = (int*)d_out;
    char* ws = (char*)d_ws;

    float*  qc   = (float*)ws;                            //  4 MB
    float*  kc   = (float*)(ws + (4ull << 20));           //  4 MB
    double* A    = (double*)(ws + (8ull << 20));          // 64 MB
    double* neg  = (double*)(ws + (72ull << 20));         // 64 MB
    double* dgo  = (double*)(ws + (136ull << 20));        // 64 KB
    double* dgi  = dgo + 8192;                            // 64 KB
    double* pout = dgi + 8192;                            //  1 MB (8*16*16*64 doubles)
    double* pin  = pout + 131072;                         //  1 MB

    coarsen_kernel<<<16384, 256, 0, stream>>>(q, k, qc, kc);
    affinity_kernel<<<2048, 256, 0, stream>>>(qc, kc, A, pout, pin);
    deg_reduce_kernel<<<64, 256, 0, stream>>>(pout, pin, dgo, dgi);
    tri_kernel<<<dim3(8, 8, 8), 512, 0, stream>>>(A, dgo, dgi, neg);
    topk_mask_kernel<<<8192, 64, 0, stream>>>(neg, out);
}